// Round 8
// baseline (318.256 us; speedup 1.0000x reference)
//
#include <hip/hip_runtime.h>
#include <math.h>

// Problem constants (fixed by setup_inputs)
#define M_TOK 16384   // B*T
#define DIM   256     // D (=K)
#define VOC   8192    // V (=N)

// GEMM tiling (R2-proven 128x128 structure, BK=64 as two 32-slices)
#define BM 128
#define BN 128
#define NBLK_N (VOC / BN)   // 64
// hi-only GEMM: d2 error sigma ~0.05 (bf16 RN 2^-9, K=256). GAP_EPS = window
// bound W = 1.5 (~30 sigma). Rows with top-2 gap < W get window-rescue:
// exact fp32 check of all codes whose APPROX d2 < approxBest + W (provably
// contains the exact argmin when 2*err <= W). Per-block top-2 makes the
// pruning sound: block fully excluded iff candV[blk] >= bound; cheap-eval
// candI[blk] iff candV[blk] < bound; full 128-code rescan iff candS[blk]
// < bound (codes beyond top-2 are unbounded there; rare).
#define GAP_EPS 1.5f

typedef unsigned short u16;
typedef unsigned long long u64;
typedef __attribute__((ext_vector_type(8))) __bf16 bf16x8;
typedef __attribute__((ext_vector_type(4))) float f32x4;

// ---- workspace layout (float-element offsets) ------------------------------
#define WS_ESQ      0                     // [8192]
#define WS_CANDPK   40960                 // [64][16384] u64 (2097152 f32 slots)
#define WS_CANDS    2138112               // [64][16384] f32
#define WS_XHI      3186688               // [16384*256] bf16 (2097152 f32 slots)
#define WS_EHI      5283840               // [8192*256] bf16 (1048576 slots)
#define WS_OFF      6332416               // [8193] int (code start offsets)
#define WS_ROWLIST  6340864               // [16384] int

// ---- out layout (float-element offsets): quantize, codes, new_embed, new_cs, new_ea
#define OUT_Q   0
#define OUT_C   4194304
#define OUT_NE  4210688
#define OUT_NCS 6307840
#define OUT_NEA 6316032

__device__ inline u16 f2bf_rn(float x) {
    unsigned u = __float_as_uint(x);
    unsigned r = u + 0x7FFFu + ((u >> 16) & 1u);   // round-to-nearest-even
    return (u16)(r >> 16);
}
__device__ inline unsigned f2key(float f) {          // order-preserving uint
    unsigned b = __float_as_uint(f);
    return (b & 0x80000000u) ? ~b : (b | 0x80000000u);
}
__device__ inline float key2f(unsigned k) {          // inverse of f2key
    unsigned b = (k & 0x80000000u) ? (k ^ 0x80000000u) : ~k;
    return __uint_as_float(b);
}

// ---------------------------------------------------------------------------
// prep: round X,E to bf16 (hi only); compute esq from fp32 originals.
__global__ __launch_bounds__(256) void prep_kernel(
    const float* __restrict__ X, const float* __restrict__ E,
    u16* __restrict__ Xhi, u16* __restrict__ Ehi,
    float* __restrict__ esq)
{
    int row  = blockIdx.x * 4 + (threadIdx.x >> 6);
    int lane = threadIdx.x & 63;
    bool isX = row < M_TOK;
    int r = isX ? row : row - M_TOK;
    const float* src = isX ? X + (size_t)row * DIM : E + (size_t)r * DIM;
    float4 v = ((const float4*)src)[lane];

    ushort4 h;
    h.x = f2bf_rn(v.x); h.y = f2bf_rn(v.y);
    h.z = f2bf_rn(v.z); h.w = f2bf_rn(v.w);
    u16* dh = isX ? Xhi : Ehi;
    *(ushort4*)&dh[(size_t)r * DIM + lane * 4] = h;

    if (!isX) {
        float s = v.x * v.x + v.y * v.y + v.z * v.z + v.w * v.w;
        #pragma unroll
        for (int o = 1; o < 64; o <<= 1) s += __shfl_xor(s, o, 64);
        if (lane == 0) esq[r] = s;
    }
}

// ---------------------------------------------------------------------------
// mfma_argmin (hi-only, R7-proven swapped-operand epilogue):
// mfma(B_frag, A_frag) gives D[code][token]; per-token top-2 over codes is an
// in-register scan of 16 values (monotone code order => lowest-index
// tie-break) + a 2-step fq-quad butterfly (24 bpermutes).
// Main loop: BK=64 per barrier-pair, 4 staged 8KB subtiles, 32 MFMAs/step.
// LDS staged via global_load_lds(16B) with XOR chunk swizzle (DMA forbids
// padding; swizzle keeps frag ds_read_b128 at <=2-way bank alias = free).
// Cand store is PACKED (key|idx u64) + second, layout [block][row] so the
// stores are coalesced 8B/4B (R7's [row][block] scatter caused 16x write-
// allocate amplification: WRITE_SIZE 70MB vs 12.6 logical). post gathers.
__global__ __launch_bounds__(256, 2) void mfma_argmin_kernel(
    const u16* __restrict__ Xhi, const u16* __restrict__ Ehi,
    const float* __restrict__ esq,
    u64* __restrict__ candPK, float* __restrict__ candS)
{
    __shared__ __align__(16) char tiles[4 * 8192];   // A_k0, A_k1, B_k0, B_k1

    const int tid = threadIdx.x;
    const int w = tid >> 6, l = tid & 63;
    const int wy = w >> 1, wx = w & 1;
    const int m0 = blockIdx.x * BM;
    const int n0 = blockIdx.y * BN;

    f32x4 acc[4][4];
    #pragma unroll
    for (int i = 0; i < 4; ++i)
        #pragma unroll
        for (int j = 0; j < 4; ++j) acc[i][j] = (f32x4)0.0f;

    // staging: wave w stages subtile w (0=A_k0 1=A_k1 2=B_k0 3=B_k1)
    const u16* gbase = (w < 2) ? Xhi : Ehi;
    const int row0   = (w < 2) ? m0 : n0;
    const int koff   = (w & 1) * 32;                 // k-half within the 64-slice
    const int swz_c = (l & 3) ^ ((l >> 3) & 3);
    const u16* gsrc0 = gbase + (size_t)(row0 + (l >> 2)) * DIM + koff + swz_c * 8;
    char* ltile = tiles + w * 8192;

    const int frow = l & 15, fq = l >> 4;
    const int fs = ((fq ^ ((frow >> 1) & 3)) * 16);
    const char* a0P = tiles + 0 * 8192 + (wy * 64 + frow) * 64 + fs;
    const char* a1P = tiles + 1 * 8192 + (wy * 64 + frow) * 64 + fs;
    const char* b0P = tiles + 2 * 8192 + (wx * 64 + frow) * 64 + fs;
    const char* b1P = tiles + 3 * 8192 + (wx * 64 + frow) * 64 + fs;

    for (int ks = 0; ks < 4; ++ks) {
        const int k0 = ks * 64;
        __syncthreads();
        #pragma unroll
        for (int i = 0; i < 8; ++i) {
            __builtin_amdgcn_global_load_lds(
                (const __attribute__((address_space(1))) unsigned int*)(gsrc0 + (size_t)i * 16 * DIM + k0),
                (__attribute__((address_space(3))) unsigned int*)(ltile + i * 1024),
                16, 0, 0);
        }
        __syncthreads();

        bf16x8 a0[4], a1[4];
        #pragma unroll
        for (int mt = 0; mt < 4; ++mt) {
            a0[mt] = *(const bf16x8*)(a0P + mt * 1024);
            a1[mt] = *(const bf16x8*)(a1P + mt * 1024);
        }
        #pragma unroll
        for (int nt = 0; nt < 4; ++nt) {
            bf16x8 b0 = *(const bf16x8*)(b0P + nt * 1024);
            bf16x8 b1 = *(const bf16x8*)(b1P + nt * 1024);
            #pragma unroll
            for (int mt = 0; mt < 4; ++mt) {
                // swapped: D[code][token]
                acc[mt][nt] = __builtin_amdgcn_mfma_f32_16x16x32_bf16(b0, a0[mt], acc[mt][nt], 0, 0, 0);
                acc[mt][nt] = __builtin_amdgcn_mfma_f32_16x16x32_bf16(b1, a1[mt], acc[mt][nt], 0, 0, 0);
            }
        }
    }

    // tiles are dead from here; re-use for the cross-wave reduce arrays
    __syncthreads();
    float* smB = (float*)tiles;            // [2][128]
    int*   smI = (int*)(tiles + 1024);     // [2][128]
    float* smS = (float*)(tiles + 2048);   // [2][128]

    // epilogue: token = wy*64 + mt*16 + frow (C-col), code = n0 + wx*64 +
    // nt*16 + fq*4 + r (C-row). Per-token top-2 of val = esq[code] - 2*dot.
    float eqv[16];
    #pragma unroll
    for (int nt = 0; nt < 4; ++nt) {
        float4 t = *(const float4*)&esq[n0 + wx * 64 + nt * 16 + fq * 4];
        eqv[nt * 4 + 0] = t.x; eqv[nt * 4 + 1] = t.y;
        eqv[nt * 4 + 2] = t.z; eqv[nt * 4 + 3] = t.w;
    }

    #pragma unroll
    for (int mt = 0; mt < 4; ++mt) {
        float b = 3.4e38f, s = 3.4e38f;
        int bi = 0;
        #pragma unroll
        for (int nt = 0; nt < 4; ++nt) {
            #pragma unroll
            for (int r = 0; r < 4; ++r) {
                float v = fmaf(-2.0f, acc[mt][nt][r], eqv[nt * 4 + r]);
                int c = n0 + wx * 64 + nt * 16 + fq * 4 + r;  // monotone in (nt,r)
                if (v < b) { s = b; b = v; bi = c; }
                else if (v < s) s = v;
            }
        }
        #pragma unroll
        for (int o = 16; o < 64; o <<= 1) {      // merge the 4 fq groups
            float ob = __shfl_xor(b, o, 64);
            int   oi = __shfl_xor(bi, o, 64);
            float os = __shfl_xor(s, o, 64);
            bool take = (ob < b) || (ob == b && oi < bi);
            float keep = take ? b : ob;
            b  = take ? ob : b;
            bi = take ? oi : bi;
            s  = fminf(fminf(s, os), keep);
        }
        if (l < 16) {                            // fq == 0 lanes
            int m_loc = wy * 64 + mt * 16 + l;
            smB[wx * 128 + m_loc] = b;
            smI[wx * 128 + m_loc] = bi;
            smS[wx * 128 + m_loc] = s;
        }
    }
    __syncthreads();
    if (tid < 128) {
        float b0 = smB[tid],       b1 = smB[128 + tid];
        int   i0 = smI[tid],       i1 = smI[128 + tid];
        float s0 = smS[tid],       s1 = smS[128 + tid];
        bool take = (b1 < b0);                 // tie -> wave 0 (lower cols)
        float b = take ? b1 : b0;
        int  bi = take ? i1 : i0;
        float s = fminf(fminf(s0, s1), take ? b0 : b1);
        size_t e = (size_t)blockIdx.y * M_TOK + (m0 + tid);   // [block][row]
        candPK[e] = ((u64)f2key(b) << 32) | (unsigned)bi;     // coalesced 8B
        candS[e]  = s;                                        // coalesced 4B
    }
}

// ---------------------------------------------------------------------------
// post: fused reduce + window-rescue + quantize. One wave per row, 4 rows per
// wave (consecutive rows reuse the gathered cand lines 4/8). Lane e holds
// block-e candidates. Packed-u64 min butterfly gives best with lowest-index
// tie-break (== reference argmin). second = min over lanes of (bestlane ?
// candS : bv). Flagged rows (gap < W) window-rescue inline; deep blocks
// (candS < bound) rescan 128 codes 4-wide. NO global atomics anywhere: codes
// go to out_codes; counts/sums are derived later by buildidx + finalize.
__global__ __launch_bounds__(256) void post_kernel(
    const float* __restrict__ X, const float* __restrict__ E,
    const float* __restrict__ esq,
    const u64* __restrict__ candPK, const float* __restrict__ candS,
    float* __restrict__ out_q, float* __restrict__ out_codes)
{
    const int lane = threadIdx.x & 63;
    const int wv   = threadIdx.x >> 6;
    const int row0 = blockIdx.x * 16 + wv * 4;

    for (int rr = 0; rr < 4; ++rr) {
        const int row = row0 + rr;
        u64   pk = candPK[(size_t)lane * M_TOK + row];
        float bs = candS[(size_t)lane * M_TOK + row];
        float bv = key2f((unsigned)(pk >> 32));

        u64 m = pk;
        #pragma unroll
        for (int o = 1; o < 64; o <<= 1) {
            u64 other = __shfl_xor(m, o, 64);
            m = (other < m) ? other : m;
        }
        float best = key2f((unsigned)(m >> 32));
        int   code = (int)(unsigned)(m & 0xFFFFFFFFull);

        float sec = (pk == m) ? bs : bv;     // bestlane unique (pk has index)
        #pragma unroll
        for (int o = 1; o < 64; o <<= 1) sec = fminf(sec, __shfl_xor(sec, o, 64));

        const float4 x4 = ((const float4*)&X[(size_t)row * DIM])[lane];

        if (sec - best < GAP_EPS) {          // wave-uniform branch
            const float bound = best + GAP_EPS;
            float bestV = 3.4e38f;
            int   bestI = 0x7FFFFFFF;
            int   bi = (int)(unsigned)(pk & 0xFFFFFFFFull);
            // cheap: exact-eval block bests inside the window (incl. code)
            u64 mask = __ballot(bv < bound);
            while (mask) {
                int src = __ffsll((unsigned long long)mask) - 1;
                mask &= mask - 1;
                int c = __shfl(bi, src, 64);
                float4 e4 = ((const float4*)&E[(size_t)c * DIM])[lane];
                float d = x4.x * e4.x + x4.y * e4.y + x4.z * e4.z + x4.w * e4.w;
                #pragma unroll
                for (int o = 1; o < 64; o <<= 1) d += __shfl_xor(d, o, 64);
                float v = fmaf(-2.0f, d, esq[c]);
                if (v < bestV || (v == bestV && c < bestI)) { bestV = v; bestI = c; }
            }
            // deep: block second also in window -> full rescan, 4-wide ILP
            u64 dmask = __ballot(bs < bound);
            while (dmask) {
                int e = __ffsll((unsigned long long)dmask) - 1;
                dmask &= dmask - 1;
                const int c0 = e * BN;
                for (int j = 0; j < BN; j += 4) {
                    float4 e0 = ((const float4*)&E[(size_t)(c0 + j + 0) * DIM])[lane];
                    float4 e1 = ((const float4*)&E[(size_t)(c0 + j + 1) * DIM])[lane];
                    float4 e2 = ((const float4*)&E[(size_t)(c0 + j + 2) * DIM])[lane];
                    float4 e3 = ((const float4*)&E[(size_t)(c0 + j + 3) * DIM])[lane];
                    float d0 = x4.x * e0.x + x4.y * e0.y + x4.z * e0.z + x4.w * e0.w;
                    float d1 = x4.x * e1.x + x4.y * e1.y + x4.z * e1.z + x4.w * e1.w;
                    float d2 = x4.x * e2.x + x4.y * e2.y + x4.z * e2.z + x4.w * e2.w;
                    float d3 = x4.x * e3.x + x4.y * e3.y + x4.z * e3.z + x4.w * e3.w;
                    #pragma unroll
                    for (int o = 1; o < 64; o <<= 1) {
                        d0 += __shfl_xor(d0, o, 64);
                        d1 += __shfl_xor(d1, o, 64);
                        d2 += __shfl_xor(d2, o, 64);
                        d3 += __shfl_xor(d3, o, 64);
                    }
                    float v0 = fmaf(-2.0f, d0, esq[c0 + j + 0]);
                    float v1 = fmaf(-2.0f, d1, esq[c0 + j + 1]);
                    float v2 = fmaf(-2.0f, d2, esq[c0 + j + 2]);
                    float v3 = fmaf(-2.0f, d3, esq[c0 + j + 3]);
                    if (v0 < bestV || (v0 == bestV && c0 + j + 0 < bestI)) { bestV = v0; bestI = c0 + j + 0; }
                    if (v1 < bestV || (v1 == bestV && c0 + j + 1 < bestI)) { bestV = v1; bestI = c0 + j + 1; }
                    if (v2 < bestV || (v2 == bestV && c0 + j + 2 < bestI)) { bestV = v2; bestI = c0 + j + 2; }
                    if (v3 < bestV || (v3 == bestV && c0 + j + 3 < bestI)) { bestV = v3; bestI = c0 + j + 3; }
                }
            }
            code = bestI;
        }

        if (lane == 0) out_codes[row] = (float)code;
        float4 e4 = ((const float4*)&E[(size_t)code * DIM])[lane];
        float4 q;
        q.x = x4.x + (e4.x - x4.x);
        q.y = x4.y + (e4.y - x4.y);
        q.z = x4.z + (e4.z - x4.z);
        q.w = x4.w + (e4.w - x4.w);
        ((float4*)&out_q[(size_t)row * DIM])[lane] = q;
    }
}

// ---------------------------------------------------------------------------
// buildidx: single-block inverted index over codes. LDS histogram (block-
// local atomics) -> LDS exclusive scan (8/thread serial + wave shfl_up scan
// + 16-wave serial combine) -> LDS-cursor fill. Replaces 4.2M global f32
// atomicAdds (old sums scatter) with 32K LDS atomics; also removes the
// 8.4MB sums/counts memset (nothing needs pre-zeroing anymore).
__global__ __launch_bounds__(1024) void buildidx_kernel(
    const float* __restrict__ codesf,
    int* __restrict__ off_g, int* __restrict__ rowlist)
{
    __shared__ int cnt[VOC];
    __shared__ int cur[VOC];
    __shared__ int wtot[16], wbase[16];
    const int tid = threadIdx.x;
    const int lane = tid & 63, wid = tid >> 6;

    #pragma unroll
    for (int i = 0; i < VOC / 1024; ++i) cnt[i * 1024 + tid] = 0;
    __syncthreads();

    int mycodes[16];
    #pragma unroll
    for (int j = 0; j < 16; ++j) {
        mycodes[j] = (int)codesf[j * 1024 + tid];
        atomicAdd(&cnt[mycodes[j]], 1);
    }
    __syncthreads();

    // exclusive scan of cnt[0..8191] -> cur (start offsets) and off_g
    const int base = tid * 8;
    int pre[8]; int s = 0;
    #pragma unroll
    for (int j = 0; j < 8; ++j) { pre[j] = s; s += cnt[base + j]; }
    int incl = s;
    #pragma unroll
    for (int o = 1; o < 64; o <<= 1) {
        int t = __shfl_up(incl, o, 64);
        if (lane >= o) incl += t;
    }
    if (lane == 63) wtot[wid] = incl;
    __syncthreads();
    if (tid == 0) {
        int a = 0;
        for (int w2 = 0; w2 < 16; ++w2) { wbase[w2] = a; a += wtot[w2]; }
    }
    __syncthreads();
    const int gb = wbase[wid] + (incl - s);
    #pragma unroll
    for (int j = 0; j < 8; ++j) {
        int o = gb + pre[j];
        cur[base + j] = o;
        off_g[base + j] = o;
    }
    if (tid == 0) off_g[VOC] = M_TOK;
    __syncthreads();

    #pragma unroll
    for (int j = 0; j < 16; ++j) {
        int p = atomicAdd(&cur[mycodes[j]], 1);
        rowlist[p] = j * 1024 + tid;
    }
}

// ---------------------------------------------------------------------------
// finalize: gather segment-sum. One wave per code v (lane owns 4 dims):
// sum X rows listed in rowlist[off[v]..off[v+1]) (avg 2 rows/code, X is
// L3-resident), then the EMA update. count derived from offsets — exact.
__global__ __launch_bounds__(256) void finalize_kernel(
    const float* __restrict__ X,
    const float* __restrict__ cs, const float* __restrict__ ea,
    const int* __restrict__ off, const int* __restrict__ rowlist,
    float* __restrict__ out_embed, float* __restrict__ out_cs,
    float* __restrict__ out_ea)
{
    const int lane = threadIdx.x & 63;
    const int v = blockIdx.x * 4 + (threadIdx.x >> 6);
    const int o0 = off[v], o1 = off[v + 1];

    float4 acc = {0.0f, 0.0f, 0.0f, 0.0f};
    for (int i = o0; i < o1; ++i) {
        int r = rowlist[i];                     // wave-uniform
        float4 x4 = ((const float4*)&X[(size_t)r * DIM])[lane];
        acc.x += x4.x; acc.y += x4.y; acc.z += x4.z; acc.w += x4.w;
    }
    const float cntv = (float)(o1 - o0);
    const float ncs = cs[v] * 0.99f + cntv * 0.01f;
    const float sc = 0.01f / 2048.0f;           // *0.01 EMA, /T codebook mean
    float4 ea4 = ((const float4*)&ea[(size_t)v * DIM])[lane];
    float4 nea, oe;
    nea.x = ea4.x * 0.99f + acc.x * sc;
    nea.y = ea4.y * 0.99f + acc.y * sc;
    nea.z = ea4.z * 0.99f + acc.z * sc;
    nea.w = ea4.w * 0.99f + acc.w * sc;
    const float den = ncs + 1e-5f;
    oe.x = nea.x / den; oe.y = nea.y / den;
    oe.z = nea.z / den; oe.w = nea.w / den;
    ((float4*)&out_ea[(size_t)v * DIM])[lane] = nea;
    ((float4*)&out_embed[(size_t)v * DIM])[lane] = oe;
    if (lane == 0) out_cs[v] = ncs;
}

// ---------------------------------------------------------------------------
extern "C" void kernel_launch(void* const* d_in, const int* in_sizes, int n_in,
                              void* d_out, int out_size, void* d_ws, size_t ws_size,
                              hipStream_t stream)
{
    const float* input     = (const float*)d_in[0];
    const float* embed     = (const float*)d_in[1];
    const float* cluster   = (const float*)d_in[2];
    const float* embed_avg = (const float*)d_in[3];

    float* out = (float*)d_out;
    float* ws  = (float*)d_ws;

    float* esq      = ws + WS_ESQ;
    u64*   candPK   = (u64*)(ws + WS_CANDPK);
    float* candS    = ws + WS_CANDS;
    u16*   Xhi      = (u16*)(ws + WS_XHI);
    u16*   Ehi      = (u16*)(ws + WS_EHI);
    int*   off      = (int*)(ws + WS_OFF);
    int*   rowlist  = (int*)(ws + WS_ROWLIST);

    prep_kernel<<<(M_TOK + VOC) / 4, 256, 0, stream>>>(
        input, embed, Xhi, Ehi, esq);

    dim3 g1(M_TOK / BM, VOC / BN);
    mfma_argmin_kernel<<<g1, 256, 0, stream>>>(
        Xhi, Ehi, esq, candPK, candS);

    post_kernel<<<M_TOK / 16, 256, 0, stream>>>(
        input, embed, esq, candPK, candS,
        out + OUT_Q, out + OUT_C);

    buildidx_kernel<<<1, 1024, 0, stream>>>(
        out + OUT_C, off, rowlist);

    finalize_kernel<<<VOC / 4, 256, 0, stream>>>(
        input, cluster, embed_avg, off, rowlist,
        out + OUT_NE, out + OUT_NCS, out + OUT_NEA);
}

// Round 9
// 295.020 us; speedup vs baseline: 1.0788x; 1.0788x over previous
//
#include <hip/hip_runtime.h>
#include <math.h>

// Problem constants (fixed by setup_inputs)
#define M_TOK 16384   // B*T
#define DIM   256     // D (=K)
#define VOC   8192    // V (=N)

// GEMM tiling (R2-proven 128x128 structure, BK=64 as two 32-slices)
#define BM 128
#define BN 128
#define NBLK_N (VOC / BN)   // 64
// hi-only GEMM: d2 error sigma ~0.05 (bf16 RN 2^-9, K=256). GAP_EPS = window
// bound W = 1.5 (~30 sigma). Rows with top-2 gap < W get window-rescue:
// exact fp32 check of all codes whose APPROX d2 < approxBest + W (provably
// contains the exact argmin when 2*err <= W). Per-block top-2 makes the
// pruning sound: block fully excluded iff candV[blk] >= bound; cheap-eval
// candI[blk] iff candV[blk] < bound; full 128-code rescan iff candS[blk]
// < bound (codes beyond top-2 are unbounded there; rare).
#define GAP_EPS 1.5f

typedef unsigned short u16;
typedef unsigned long long u64;
typedef __attribute__((ext_vector_type(8))) __bf16 bf16x8;
typedef __attribute__((ext_vector_type(4))) float f32x4;

// ---- workspace layout (float-element offsets) ------------------------------
#define WS_ESQ      0                     // [8192]
#define WS_CANDPK   40960                 // [64][16384] u64 (2097152 f32 slots)
#define WS_CANDS    2138112               // [64][16384] f32
#define WS_XHI      3186688               // [16384*256] bf16 (2097152 f32 slots)
#define WS_EHI      5283840               // [8192*256] bf16 (1048576 slots)
#define WS_COUNTS   6332416               // [8192]
#define WS_SUMS     6340608               // [8192*256]
// prep zeroes COUNTS..SUMS inline: 2,105,344 floats = 526,336 float4 (16B-aligned)
#define ZERO_F4     526336

// ---- out layout (float-element offsets): quantize, codes, new_embed, new_cs, new_ea
#define OUT_Q   0
#define OUT_C   4194304
#define OUT_NE  4210688
#define OUT_NCS 6307840
#define OUT_NEA 6316032

__device__ inline u16 f2bf_rn(float x) {
    unsigned u = __float_as_uint(x);
    unsigned r = u + 0x7FFFu + ((u >> 16) & 1u);   // round-to-nearest-even
    return (u16)(r >> 16);
}
__device__ inline unsigned f2key(float f) {          // order-preserving uint
    unsigned b = __float_as_uint(f);
    return (b & 0x80000000u) ? ~b : (b | 0x80000000u);
}
__device__ inline float key2f(unsigned k) {          // inverse of f2key
    unsigned b = (k & 0x80000000u) ? (k ^ 0x80000000u) : ~k;
    return __uint_as_float(b);
}

// ---------------------------------------------------------------------------
// prep: round X,E to bf16 (hi only); compute esq from fp32 originals.
// Also zeroes counts+sums inline (one conditional float4 store per thread)
// so the separate hipMemsetAsync dispatch (~25-30us of launch overhead) goes.
__global__ __launch_bounds__(256) void prep_kernel(
    const float* __restrict__ X, const float* __restrict__ E,
    u16* __restrict__ Xhi, u16* __restrict__ Ehi,
    float* __restrict__ esq, float4* __restrict__ zbase)
{
    int row  = blockIdx.x * 4 + (threadIdx.x >> 6);
    int lane = threadIdx.x & 63;
    bool isX = row < M_TOK;
    int r = isX ? row : row - M_TOK;
    const float* src = isX ? X + (size_t)row * DIM : E + (size_t)r * DIM;
    float4 v = ((const float4*)src)[lane];

    ushort4 h;
    h.x = f2bf_rn(v.x); h.y = f2bf_rn(v.y);
    h.z = f2bf_rn(v.z); h.w = f2bf_rn(v.w);
    u16* dh = isX ? Xhi : Ehi;
    *(ushort4*)&dh[(size_t)r * DIM + lane * 4] = h;

    if (!isX) {
        float s = v.x * v.x + v.y * v.y + v.z * v.z + v.w * v.w;
        #pragma unroll
        for (int o = 1; o < 64; o <<= 1) s += __shfl_xor(s, o, 64);
        if (lane == 0) esq[r] = s;
    }

    int gid = blockIdx.x * 256 + threadIdx.x;
    if (gid < ZERO_F4) {
        float4 z = {0.0f, 0.0f, 0.0f, 0.0f};
        zbase[gid] = z;
    }
}

// ---------------------------------------------------------------------------
// mfma_argmin (hi-only, R8-proven, byte-identical): swapped-operand epilogue
// mfma(B_frag, A_frag) gives D[code][token]; per-token top-2 over codes is an
// in-register scan of 16 values (monotone code order => lowest-index
// tie-break) + a 2-step fq-quad butterfly (24 bpermutes).
// Main loop: BK=64 per barrier-pair, 4 staged 8KB subtiles, 32 MFMAs/step.
// LDS staged via global_load_lds(16B) with XOR chunk swizzle (DMA forbids
// padding; swizzle keeps frag ds_read_b128 at <=2-way bank alias = free).
// Cand store PACKED (key|idx u64) + second, [block][row] coalesced 8B/4B
// (a [row][block] scatter costs 16x write-allocate: R7 measured 70MB writes).
__global__ __launch_bounds__(256, 2) void mfma_argmin_kernel(
    const u16* __restrict__ Xhi, const u16* __restrict__ Ehi,
    const float* __restrict__ esq,
    u64* __restrict__ candPK, float* __restrict__ candS)
{
    __shared__ __align__(16) char tiles[4 * 8192];   // A_k0, A_k1, B_k0, B_k1

    const int tid = threadIdx.x;
    const int w = tid >> 6, l = tid & 63;
    const int wy = w >> 1, wx = w & 1;
    const int m0 = blockIdx.x * BM;
    const int n0 = blockIdx.y * BN;

    f32x4 acc[4][4];
    #pragma unroll
    for (int i = 0; i < 4; ++i)
        #pragma unroll
        for (int j = 0; j < 4; ++j) acc[i][j] = (f32x4)0.0f;

    // staging: wave w stages subtile w (0=A_k0 1=A_k1 2=B_k0 3=B_k1)
    const u16* gbase = (w < 2) ? Xhi : Ehi;
    const int row0   = (w < 2) ? m0 : n0;
    const int koff   = (w & 1) * 32;                 // k-half within the 64-slice
    const int swz_c = (l & 3) ^ ((l >> 3) & 3);
    const u16* gsrc0 = gbase + (size_t)(row0 + (l >> 2)) * DIM + koff + swz_c * 8;
    char* ltile = tiles + w * 8192;

    const int frow = l & 15, fq = l >> 4;
    const int fs = ((fq ^ ((frow >> 1) & 3)) * 16);
    const char* a0P = tiles + 0 * 8192 + (wy * 64 + frow) * 64 + fs;
    const char* a1P = tiles + 1 * 8192 + (wy * 64 + frow) * 64 + fs;
    const char* b0P = tiles + 2 * 8192 + (wx * 64 + frow) * 64 + fs;
    const char* b1P = tiles + 3 * 8192 + (wx * 64 + frow) * 64 + fs;

    for (int ks = 0; ks < 4; ++ks) {
        const int k0 = ks * 64;
        __syncthreads();
        #pragma unroll
        for (int i = 0; i < 8; ++i) {
            __builtin_amdgcn_global_load_lds(
                (const __attribute__((address_space(1))) unsigned int*)(gsrc0 + (size_t)i * 16 * DIM + k0),
                (__attribute__((address_space(3))) unsigned int*)(ltile + i * 1024),
                16, 0, 0);
        }
        __syncthreads();

        bf16x8 a0[4], a1[4];
        #pragma unroll
        for (int mt = 0; mt < 4; ++mt) {
            a0[mt] = *(const bf16x8*)(a0P + mt * 1024);
            a1[mt] = *(const bf16x8*)(a1P + mt * 1024);
        }
        #pragma unroll
        for (int nt = 0; nt < 4; ++nt) {
            bf16x8 b0 = *(const bf16x8*)(b0P + nt * 1024);
            bf16x8 b1 = *(const bf16x8*)(b1P + nt * 1024);
            #pragma unroll
            for (int mt = 0; mt < 4; ++mt) {
                // swapped: D[code][token]
                acc[mt][nt] = __builtin_amdgcn_mfma_f32_16x16x32_bf16(b0, a0[mt], acc[mt][nt], 0, 0, 0);
                acc[mt][nt] = __builtin_amdgcn_mfma_f32_16x16x32_bf16(b1, a1[mt], acc[mt][nt], 0, 0, 0);
            }
        }
    }

    // tiles are dead from here; re-use for the cross-wave reduce arrays
    __syncthreads();
    float* smB = (float*)tiles;            // [2][128]
    int*   smI = (int*)(tiles + 1024);     // [2][128]
    float* smS = (float*)(tiles + 2048);   // [2][128]

    // epilogue: token = wy*64 + mt*16 + frow (C-col), code = n0 + wx*64 +
    // nt*16 + fq*4 + r (C-row). Per-token top-2 of val = esq[code] - 2*dot.
    float eqv[16];
    #pragma unroll
    for (int nt = 0; nt < 4; ++nt) {
        float4 t = *(const float4*)&esq[n0 + wx * 64 + nt * 16 + fq * 4];
        eqv[nt * 4 + 0] = t.x; eqv[nt * 4 + 1] = t.y;
        eqv[nt * 4 + 2] = t.z; eqv[nt * 4 + 3] = t.w;
    }

    #pragma unroll
    for (int mt = 0; mt < 4; ++mt) {
        float b = 3.4e38f, s = 3.4e38f;
        int bi = 0;
        #pragma unroll
        for (int nt = 0; nt < 4; ++nt) {
            #pragma unroll
            for (int r = 0; r < 4; ++r) {
                float v = fmaf(-2.0f, acc[mt][nt][r], eqv[nt * 4 + r]);
                int c = n0 + wx * 64 + nt * 16 + fq * 4 + r;  // monotone in (nt,r)
                if (v < b) { s = b; b = v; bi = c; }
                else if (v < s) s = v;
            }
        }
        #pragma unroll
        for (int o = 16; o < 64; o <<= 1) {      // merge the 4 fq groups
            float ob = __shfl_xor(b, o, 64);
            int   oi = __shfl_xor(bi, o, 64);
            float os = __shfl_xor(s, o, 64);
            bool take = (ob < b) || (ob == b && oi < bi);
            float keep = take ? b : ob;
            b  = take ? ob : b;
            bi = take ? oi : bi;
            s  = fminf(fminf(s, os), keep);
        }
        if (l < 16) {                            // fq == 0 lanes
            int m_loc = wy * 64 + mt * 16 + l;
            smB[wx * 128 + m_loc] = b;
            smI[wx * 128 + m_loc] = bi;
            smS[wx * 128 + m_loc] = s;
        }
    }
    __syncthreads();
    if (tid < 128) {
        float b0 = smB[tid],       b1 = smB[128 + tid];
        int   i0 = smI[tid],       i1 = smI[128 + tid];
        float s0 = smS[tid],       s1 = smS[128 + tid];
        bool take = (b1 < b0);                 // tie -> wave 0 (lower cols)
        float b = take ? b1 : b0;
        int  bi = take ? i1 : i0;
        float s = fminf(fminf(s0, s1), take ? b0 : b1);
        size_t e = (size_t)blockIdx.y * M_TOK + (m0 + tid);   // [block][row]
        candPK[e] = ((u64)f2key(b) << 32) | (unsigned)bi;     // coalesced 8B
        candS[e]  = s;                                        // coalesced 4B
    }
}

// ---------------------------------------------------------------------------
// post: fused reduce + window-rescue + assign (R7-proven semantics, atomics
// for counts/sums — the R8 buildidx detour measured WORSE). Cand access is
// now coalesced on BOTH sides: argmin stores [block][row]; post loads 4 rows
// x 64 blocks in 32B segments and transposes through 3KB LDS; each wave then
// reads its row's 64 entries conflict-free. One wave per row. Packed-u64 min
// butterfly gives best with lowest-index tie-break (== reference argmin);
// second = min over lanes of (bestlane ? candS : bv). Flagged rows (gap < W)
// window-rescue inline; deep blocks rescan 128 codes 4-wide. X row loaded
// once, reused for exact dot + STE quantize.
__global__ __launch_bounds__(256) void post_kernel(
    const float* __restrict__ X, const float* __restrict__ E,
    const float* __restrict__ esq,
    const u64* __restrict__ candPK, const float* __restrict__ candS,
    float* __restrict__ out_q, float* __restrict__ out_codes,
    float* __restrict__ counts, float* __restrict__ sums)
{
    __shared__ u64   pkS[4][64];
    __shared__ float sS[4][64];
    const int lane = threadIdx.x & 63;
    const int wv   = threadIdx.x >> 6;
    const int row0 = blockIdx.x * 4;

    {   // cooperative transposed load: thread t -> block e = t>>2, row rr = t&3
        const int e = threadIdx.x >> 2, rr = threadIdx.x & 3;
        pkS[rr][e] = candPK[(size_t)e * M_TOK + row0 + rr];
        sS[rr][e]  = candS [(size_t)e * M_TOK + row0 + rr];
    }
    __syncthreads();

    const int row = row0 + wv;
    u64   pk = pkS[wv][lane];
    float bs = sS[wv][lane];
    float bv = key2f((unsigned)(pk >> 32));

    u64 m = pk;
    #pragma unroll
    for (int o = 1; o < 64; o <<= 1) {
        u64 other = __shfl_xor(m, o, 64);
        m = (other < m) ? other : m;
    }
    float best = key2f((unsigned)(m >> 32));
    int   code = (int)(unsigned)(m & 0xFFFFFFFFull);

    float sec = (pk == m) ? bs : bv;     // bestlane unique (pk has index)
    #pragma unroll
    for (int o = 1; o < 64; o <<= 1) sec = fminf(sec, __shfl_xor(sec, o, 64));

    const float4 x4 = ((const float4*)&X[(size_t)row * DIM])[lane];

    if (sec - best < GAP_EPS) {          // wave-uniform branch
        const float bound = best + GAP_EPS;
        float bestV = 3.4e38f;
        int   bestI = 0x7FFFFFFF;
        int   bi = (int)(unsigned)(pk & 0xFFFFFFFFull);
        // cheap: exact-eval block bests inside the window (incl. code)
        u64 mask = __ballot(bv < bound);
        while (mask) {
            int src = __ffsll((unsigned long long)mask) - 1;
            mask &= mask - 1;
            int c = __shfl(bi, src, 64);
            float4 e4 = ((const float4*)&E[(size_t)c * DIM])[lane];
            float d = x4.x * e4.x + x4.y * e4.y + x4.z * e4.z + x4.w * e4.w;
            #pragma unroll
            for (int o = 1; o < 64; o <<= 1) d += __shfl_xor(d, o, 64);
            float v = fmaf(-2.0f, d, esq[c]);
            if (v < bestV || (v == bestV && c < bestI)) { bestV = v; bestI = c; }
        }
        // deep: block second also in window -> full rescan, 4-wide ILP
        u64 dmask = __ballot(bs < bound);
        while (dmask) {
            int e = __ffsll((unsigned long long)dmask) - 1;
            dmask &= dmask - 1;
            const int c0 = e * BN;
            for (int j = 0; j < BN; j += 4) {
                float4 e0 = ((const float4*)&E[(size_t)(c0 + j + 0) * DIM])[lane];
                float4 e1 = ((const float4*)&E[(size_t)(c0 + j + 1) * DIM])[lane];
                float4 e2 = ((const float4*)&E[(size_t)(c0 + j + 2) * DIM])[lane];
                float4 e3 = ((const float4*)&E[(size_t)(c0 + j + 3) * DIM])[lane];
                float d0 = x4.x * e0.x + x4.y * e0.y + x4.z * e0.z + x4.w * e0.w;
                float d1 = x4.x * e1.x + x4.y * e1.y + x4.z * e1.z + x4.w * e1.w;
                float d2 = x4.x * e2.x + x4.y * e2.y + x4.z * e2.z + x4.w * e2.w;
                float d3 = x4.x * e3.x + x4.y * e3.y + x4.z * e3.z + x4.w * e3.w;
                #pragma unroll
                for (int o = 1; o < 64; o <<= 1) {
                    d0 += __shfl_xor(d0, o, 64);
                    d1 += __shfl_xor(d1, o, 64);
                    d2 += __shfl_xor(d2, o, 64);
                    d3 += __shfl_xor(d3, o, 64);
                }
                float v0 = fmaf(-2.0f, d0, esq[c0 + j + 0]);
                float v1 = fmaf(-2.0f, d1, esq[c0 + j + 1]);
                float v2 = fmaf(-2.0f, d2, esq[c0 + j + 2]);
                float v3 = fmaf(-2.0f, d3, esq[c0 + j + 3]);
                if (v0 < bestV || (v0 == bestV && c0 + j + 0 < bestI)) { bestV = v0; bestI = c0 + j + 0; }
                if (v1 < bestV || (v1 == bestV && c0 + j + 1 < bestI)) { bestV = v1; bestI = c0 + j + 1; }
                if (v2 < bestV || (v2 == bestV && c0 + j + 2 < bestI)) { bestV = v2; bestI = c0 + j + 2; }
                if (v3 < bestV || (v3 == bestV && c0 + j + 3 < bestI)) { bestV = v3; bestI = c0 + j + 3; }
            }
        }
        code = bestI;
    }

    // assign: codes, STE quantize, EMA scatter
    if (lane == 0) {
        out_codes[row] = (float)code;
        atomicAdd(&counts[code], 1.0f);
    }
    float4 e4 = ((const float4*)&E[(size_t)code * DIM])[lane];
    float4 q;
    q.x = x4.x + (e4.x - x4.x);
    q.y = x4.y + (e4.y - x4.y);
    q.z = x4.z + (e4.z - x4.z);
    q.w = x4.w + (e4.w - x4.w);
    ((float4*)&out_q[(size_t)row * DIM])[lane] = q;
    float* s = &sums[(size_t)code * DIM + lane * 4];
    atomicAdd(s + 0, x4.x);
    atomicAdd(s + 1, x4.y);
    atomicAdd(s + 2, x4.z);
    atomicAdd(s + 3, x4.w);
}

// ---------------------------------------------------------------------------
__global__ __launch_bounds__(256) void finalize_kernel(
    const float* __restrict__ cs, const float* __restrict__ ea,
    const float* __restrict__ counts, const float* __restrict__ sums,
    float* __restrict__ out_embed, float* __restrict__ out_cs,
    float* __restrict__ out_ea)
{
    int vd = blockIdx.x * 256 + threadIdx.x;
    int v = vd >> 8, d = vd & 255;
    float cnt = counts[v];
    float ncs = cs[v] * 0.99f + cnt * 0.01f;
    float cb  = sums[vd] * (1.0f / 2048.0f);
    float nea = ea[vd] * 0.99f + cb * 0.01f;
    out_ea[vd] = nea;
    out_embed[vd] = nea / (ncs + 1e-5f);
    if (d == 0) out_cs[v] = ncs;
}

// ---------------------------------------------------------------------------
extern "C" void kernel_launch(void* const* d_in, const int* in_sizes, int n_in,
                              void* d_out, int out_size, void* d_ws, size_t ws_size,
                              hipStream_t stream)
{
    const float* input     = (const float*)d_in[0];
    const float* embed     = (const float*)d_in[1];
    const float* cluster   = (const float*)d_in[2];
    const float* embed_avg = (const float*)d_in[3];

    float* out = (float*)d_out;
    float* ws  = (float*)d_ws;

    float* esq      = ws + WS_ESQ;
    u64*   candPK   = (u64*)(ws + WS_CANDPK);
    float* candS    = ws + WS_CANDS;
    u16*   Xhi      = (u16*)(ws + WS_XHI);
    u16*   Ehi      = (u16*)(ws + WS_EHI);
    float* counts   = ws + WS_COUNTS;
    float* sums     = ws + WS_SUMS;

    prep_kernel<<<(M_TOK + VOC) / 4, 256, 0, stream>>>(
        input, embed, Xhi, Ehi, esq, (float4*)counts);

    dim3 g1(M_TOK / BM, VOC / BN);
    mfma_argmin_kernel<<<g1, 256, 0, stream>>>(
        Xhi, Ehi, esq, candPK, candS);

    post_kernel<<<M_TOK / 4, 256, 0, stream>>>(
        input, embed, esq, candPK, candS,
        out + OUT_Q, out + OUT_C, counts, sums);

    finalize_kernel<<<(VOC * DIM) / 256, 256, 0, stream>>>(
        cluster, embed_avg, counts, sums,
        out + OUT_NE, out + OUT_NCS, out + OUT_NEA);
}